// Round 1
// baseline (42.492 us; speedup 1.0000x reference)
//
#include <hip/hip_runtime.h>
#include <math.h>

// Epps-Pulley test statistic, B=16 rows of N=4096 fp32.
//   term1 = sum_{i,j} exp(-0.5 (xs_i - xs_j)^2) / N^2      <-- dominant, O(N^2)
//   term2 = -2/(N K) sum_{i,k} exp(-0.5 (xs_i - g_k)^2)
//   term3 = const
// Factorization: exp(-0.5(a-b)^2) = w_a * w_b * exp(a*b), w = exp(-0.5 x^2).
// Symmetry: only tile-pairs ti<=tj; off-diag counted x2.

#define N_ELEM 4096
#define BATCH 16
#define NPTS 17
#define NTILE 16            // N_ELEM / 256
#define NPAIRS 136          // NTILE*(NTILE+1)/2
#define L2E 1.4426950408889634f
#define HL2E 0.7213475204444817f   // 0.5*log2(e)

#if defined(__has_builtin)
#if __has_builtin(__builtin_amdgcn_exp2f)
#define EXP2(x) __builtin_amdgcn_exp2f(x)
#else
#define EXP2(x) exp2f(x)
#endif
#else
#define EXP2(x) exp2f(x)
#endif

// ws layout (doubles): [0..15] mean, [16..31] istd, [32..47] pair-sum accum

__global__ __launch_bounds__(256) void ep_stats(const float* __restrict__ x,
                                                double* __restrict__ ws) {
    __shared__ double red[8];
    const int b = blockIdx.x;
    const int tid = threadIdx.x;
    const float* xr = x + b * N_ELEM;
    double s = 0.0, s2 = 0.0;
    for (int i = tid; i < N_ELEM; i += 256) {
        double v = (double)xr[i];
        s += v;
        s2 += v * v;
    }
    const int lane = tid & 63, w = tid >> 6;
#pragma unroll
    for (int off = 32; off > 0; off >>= 1) {
        s += __shfl_down(s, off, 64);
        s2 += __shfl_down(s2, off, 64);
    }
    if (lane == 0) { red[w] = s; red[4 + w] = s2; }
    __syncthreads();
    if (tid == 0) {
        double S  = red[0] + red[1] + red[2] + red[3];
        double S2 = red[4] + red[5] + red[6] + red[7];
        double mean = S / (double)N_ELEM;
        double var  = (S2 - (double)N_ELEM * mean * mean) / (double)(N_ELEM - 1);
        double sd   = sqrt(var) + 1e-6;   // torch-style: std (ddof=1) + EPS
        ws[b]      = mean;
        ws[16 + b] = 1.0 / sd;
        ws[32 + b] = 0.0;                 // zero accumulator every call
    }
}

__global__ __launch_bounds__(256) void ep_pairs(const float* __restrict__ x,
                                                double* __restrict__ ws) {
    __shared__ float2 tile[256];
    __shared__ double red[4];
    const int tid = threadIdx.x;
    const int blk = blockIdx.x;
    const int b = blk / NPAIRS;
    int p = blk - b * NPAIRS;
    int ti = 0;
    while (p >= NTILE - ti) { p -= NTILE - ti; ++ti; }   // uniform, <=16 iters
    const int tj = ti + p;

    const float mean = (float)ws[b];
    const float istd = (float)ws[16 + b];
    const float* xr = x + b * N_ELEM;

    const float xi = (xr[ti * 256 + tid] - mean) * istd;
    const float xj = (xr[tj * 256 + tid] - mean) * istd;
    tile[tid] = make_float2(xj, EXP2(-HL2E * xj * xj));   // {x_j, w_j}
    const float ai = xi * L2E;                            // exp(xi*xj)=exp2(ai*xj)
    const float wi = EXP2(-HL2E * xi * xi);
    __syncthreads();

    float a0 = 0.f, a1 = 0.f, a2 = 0.f, a3 = 0.f;
#pragma unroll 4
    for (int k = 0; k < 256; k += 4) {
        float2 p0 = tile[k + 0];
        float2 p1 = tile[k + 1];
        float2 p2 = tile[k + 2];
        float2 p3 = tile[k + 3];
        a0 = fmaf(p0.y, EXP2(ai * p0.x), a0);
        a1 = fmaf(p1.y, EXP2(ai * p1.x), a1);
        a2 = fmaf(p2.y, EXP2(ai * p2.x), a2);
        a3 = fmaf(p3.y, EXP2(ai * p3.x), a3);
    }
    float v = ((a0 + a1) + (a2 + a3)) * wi;
#pragma unroll
    for (int off = 32; off > 0; off >>= 1) v += __shfl_down(v, off, 64);
    if ((tid & 63) == 0) red[tid >> 6] = (double)v;
    __syncthreads();
    if (tid == 0) {
        double bsum = red[0] + red[1] + red[2] + red[3];
        if (ti != tj) bsum *= 2.0;        // off-diagonal tiles count both orders
        atomicAdd(&ws[32 + b], bsum);
    }
}

// Giles' single-precision erfinv — same polynomial XLA uses for f32 erfinv.
__device__ __forceinline__ float erfinv_f(float y) {
    float w = -logf((1.0f - y) * (1.0f + y));
    float p;
    if (w < 5.0f) {
        w = w - 2.5f;
        p = 2.81022636e-08f;
        p = fmaf(p, w, 3.43273939e-07f);
        p = fmaf(p, w, -3.5233877e-06f);
        p = fmaf(p, w, -4.39150654e-06f);
        p = fmaf(p, w, 0.00021858087f);
        p = fmaf(p, w, -0.00125372503f);
        p = fmaf(p, w, -0.00417768164f);
        p = fmaf(p, w, 0.246640727f);
        p = fmaf(p, w, 1.50140941f);
    } else {
        w = sqrtf(w) - 3.0f;
        p = -0.000200214257f;
        p = fmaf(p, w, 0.000100950558f);
        p = fmaf(p, w, 0.00134934322f);
        p = fmaf(p, w, -0.00367342844f);
        p = fmaf(p, w, 0.00573950773f);
        p = fmaf(p, w, -0.0076224613f);
        p = fmaf(p, w, 0.00943887047f);
        p = fmaf(p, w, 1.00167406f);
        p = fmaf(p, w, 2.83297682f);
    }
    return p * y;
}

__global__ __launch_bounds__(256) void ep_tail(const float* __restrict__ x,
                                               const double* __restrict__ ws,
                                               float* __restrict__ out) {
    __shared__ float g[NPTS];
    __shared__ double red[4];
    const int b = blockIdx.x;
    const int tid = threadIdx.x;
    if (tid < NPTS) {
        float q = 0.01f + 0.06125f * (float)tid;   // linspace(0.01, 0.99, 17)
        g[tid] = erfinv_f(2.0f * q - 1.0f) * 1.41421356237309515f;
    }
    __syncthreads();

    const float mean = (float)ws[b];
    const float istd = (float)ws[16 + b];
    const float* xr = x + b * N_ELEM;

    // term2 cross-kernel sum
    float acc = 0.f;
    for (int i = tid; i < N_ELEM; i += 256) {
        float xs = (xr[i] - mean) * istd;
#pragma unroll
        for (int k = 0; k < NPTS; ++k) {
            float d = xs - g[k];
            acc += EXP2(-HL2E * d * d);
        }
    }
    float v = acc;
#pragma unroll
    for (int off = 32; off > 0; off >>= 1) v += __shfl_down(v, off, 64);
    if ((tid & 63) == 0) red[tid >> 6] = (double)v;
    __syncthreads();
    double sum2 = 0.0;
    if (tid == 0) sum2 = red[0] + red[1] + red[2] + red[3];

    // term3 (constant): 17x17 pair sum
    float t3 = 0.f;
    for (int pp = tid; pp < NPTS * NPTS; pp += 256) {
        int kk = pp / NPTS, ll = pp - kk * NPTS;
        float d = g[kk] - g[ll];
        t3 += EXP2(-HL2E * d * d);
    }
    __syncthreads();   // tid0 finished reading red above
    float v3 = t3;
#pragma unroll
    for (int off = 32; off > 0; off >>= 1) v3 += __shfl_down(v3, off, 64);
    if ((tid & 63) == 0) red[tid >> 6] = (double)v3;
    __syncthreads();
    if (tid == 0) {
        double term3 = (red[0] + red[1] + red[2] + red[3]) / (double)(NPTS * NPTS);
        double term1 = ws[32 + b] / ((double)N_ELEM * (double)N_ELEM);
        double term2 = -2.0 * sum2 / ((double)N_ELEM * (double)NPTS);
        out[b] = (float)(term1 + term2 + term3);
    }
}

extern "C" void kernel_launch(void* const* d_in, const int* in_sizes, int n_in,
                              void* d_out, int out_size, void* d_ws, size_t ws_size,
                              hipStream_t stream) {
    const float* x = (const float*)d_in[0];
    float* out = (float*)d_out;
    double* ws = (double*)d_ws;
    hipLaunchKernelGGL(ep_stats, dim3(BATCH), dim3(256), 0, stream, x, ws);
    hipLaunchKernelGGL(ep_pairs, dim3(BATCH * NPAIRS), dim3(256), 0, stream, x, ws);
    hipLaunchKernelGGL(ep_tail, dim3(BATCH), dim3(256), 0, stream, x, ws, out);
}

// Round 2
// 24.725 us; speedup vs baseline: 1.7186x; 1.7186x over previous
//
#include <hip/hip_runtime.h>
#include <math.h>

// Epps-Pulley statistic, B=16 rows, N=4096 fp32, single fused kernel.
// term1 via Mercer/Taylor moments: sum_ij wi wj e^{xi xj} = sum_n S_n^2/n!,
//   S_n = sum_i wi xi^n, wi = e^{-xi^2/2}.  M=48 moments: tail < 1e-9.
// term2 direct: e^{-(x-g)^2/2} = w * exp2(L2E*x*g - HL2E*g^2)  (1 fma + 1 exp).
// term3: tiny constant pair sum. All cross-thread reductions promoted to f64.

#define N_ELEM 4096
#define BATCH 16
#define NPTS 17
#define NM 49                     // moments n = 0..48
#define L2E 1.4426950408889634f
#define HL2E 0.7213475204444817f  // 0.5*log2(e)

#if defined(__has_builtin)
#if __has_builtin(__builtin_amdgcn_exp2f)
#define EXP2(x) __builtin_amdgcn_exp2f(x)
#else
#define EXP2(x) exp2f(x)
#endif
#else
#define EXP2(x) exp2f(x)
#endif

// Giles' single-precision erfinv — matches XLA's f32 erfinv path.
__device__ __forceinline__ float erfinv_f(float y) {
    float w = -logf((1.0f - y) * (1.0f + y));
    float p;
    if (w < 5.0f) {
        w = w - 2.5f;
        p = 2.81022636e-08f;
        p = fmaf(p, w, 3.43273939e-07f);
        p = fmaf(p, w, -3.5233877e-06f);
        p = fmaf(p, w, -4.39150654e-06f);
        p = fmaf(p, w, 0.00021858087f);
        p = fmaf(p, w, -0.00125372503f);
        p = fmaf(p, w, -0.00417768164f);
        p = fmaf(p, w, 0.246640727f);
        p = fmaf(p, w, 1.50140941f);
    } else {
        w = sqrtf(w) - 3.0f;
        p = -0.000200214257f;
        p = fmaf(p, w, 0.000100950558f);
        p = fmaf(p, w, 0.00134934322f);
        p = fmaf(p, w, -0.00367342844f);
        p = fmaf(p, w, 0.00573950773f);
        p = fmaf(p, w, -0.0076224613f);
        p = fmaf(p, w, 0.00943887047f);
        p = fmaf(p, w, 1.00167406f);
        p = fmaf(p, w, 2.83297682f);
    }
    return p * y;
}

__global__ __launch_bounds__(256) void ep_fused(const float* __restrict__ x,
                                                float* __restrict__ out) {
    __shared__ double sred[8];
    __shared__ double stats[2];
    __shared__ float gl[NPTS], lgl[NPTS];
    __shared__ double mred[4][NM];
    __shared__ double cred[NM];
    __shared__ double t2red[4], t3red[4];

    const int b = blockIdx.x, tid = threadIdx.x;
    const int lane = tid & 63, wv = tid >> 6;
    const float* xr = x + b * N_ELEM;
    const float4* xr4 = (const float4*)xr;

    // reference points g_k (f32, same as round-1 which matched bitwise)
    if (tid < NPTS) {
        float q = 0.01f + 0.06125f * (float)tid;   // linspace(0.01,0.99,17)
        float g = erfinv_f(2.0f * q - 1.0f) * 1.41421356237309515f;
        gl[tid] = g;
        lgl[tid] = -HL2E * g * g;
    }

    // ---- Phase A: mean / unbiased std (f64) ----
    double s = 0.0, s2 = 0.0;
#pragma unroll
    for (int e = 0; e < 4; ++e) {
        float4 v = xr4[tid + 256 * e];
        double d0 = v.x, d1 = v.y, d2 = v.z, d3 = v.w;
        s  += (d0 + d1) + (d2 + d3);
        s2 += (d0 * d0 + d1 * d1) + (d2 * d2 + d3 * d3);
    }
#pragma unroll
    for (int off = 32; off > 0; off >>= 1) {
        s  += __shfl_down(s, off, 64);
        s2 += __shfl_down(s2, off, 64);
    }
    if (lane == 0) { sred[wv] = s; sred[4 + wv] = s2; }
    __syncthreads();
    if (tid == 0) {
        double Sa = (sred[0] + sred[1]) + (sred[2] + sred[3]);
        double Sb = (sred[4] + sred[5]) + (sred[6] + sred[7]);
        double mean = Sa / (double)N_ELEM;
        double var  = (Sb - (double)N_ELEM * mean * mean) / (double)(N_ELEM - 1);
        stats[0] = mean;
        stats[1] = 1.0 / (sqrt(var) + 1e-6);   // torch std(ddof=1) + EPS
    }
    __syncthreads();
    const double mean = stats[0], istd = stats[1];

    // ---- Phase B: normalized elements + Gaussian weights (f32 regs) ----
    float xf[16], wf[16];
#pragma unroll
    for (int e = 0; e < 4; ++e) {
        float4 v = xr4[tid + 256 * e];
        xf[4 * e + 0] = (float)(((double)v.x - mean) * istd);
        xf[4 * e + 1] = (float)(((double)v.y - mean) * istd);
        xf[4 * e + 2] = (float)(((double)v.z - mean) * istd);
        xf[4 * e + 3] = (float)(((double)v.w - mean) * istd);
    }
#pragma unroll
    for (int e = 0; e < 16; ++e) wf[e] = EXP2(-HL2E * xf[e] * xf[e]);

    // moments S_n = sum_i w_i x_i^n (4 interleaved power chains for ILP)
    float S[NM];
#pragma unroll
    for (int n = 0; n < NM; ++n) S[n] = 0.f;
#pragma unroll
    for (int e = 0; e < 16; e += 4) {
        float p0 = wf[e], p1 = wf[e + 1], p2 = wf[e + 2], p3 = wf[e + 3];
        float y0 = xf[e], y1 = xf[e + 1], y2 = xf[e + 2], y3 = xf[e + 3];
#pragma unroll
        for (int n = 0; n < NM; ++n) {
            S[n] += (p0 + p1) + (p2 + p3);
            p0 *= y0; p1 *= y1; p2 *= y2; p3 *= y3;
        }
    }
    // wave reduce (f32), promote to f64 per wave
#pragma unroll
    for (int n = 0; n < NM; ++n) {
        float v = S[n];
#pragma unroll
        for (int off = 32; off > 0; off >>= 1) v += __shfl_down(v, off, 64);
        if (lane == 0) mred[wv][n] = (double)v;
    }
    __syncthreads();
    if (tid < NM) {
        double Sn = (mred[0][tid] + mred[1][tid]) + (mred[2][tid] + mred[3][tid]);
        double f = 1.0;
        for (int i = 2; i <= tid; ++i) f *= (double)i;   // n!
        cred[tid] = Sn * Sn / f;
    }

    // ---- Phase C: term2 cross-kernel (reuses xf/wf in regs) ----
    float greg[NPTS], lgreg[NPTS];
#pragma unroll
    for (int k = 0; k < NPTS; ++k) { greg[k] = gl[k]; lgreg[k] = lgl[k]; }
    float acc2 = 0.f;
#pragma unroll
    for (int e = 0; e < 16; ++e) {
        float a = xf[e] * L2E;
        float t = 0.f;
#pragma unroll
        for (int k = 0; k < NPTS; ++k)
            t += EXP2(fmaf(a, greg[k], lgreg[k]));
        acc2 = fmaf(wf[e], t, acc2);
    }
    {
        double v = (double)acc2;
#pragma unroll
        for (int off = 32; off > 0; off >>= 1) v += __shfl_down(v, off, 64);
        if (lane == 0) t2red[wv] = v;
    }

    // ---- term3: constant 17x17 pair sum ----
    float acc3 = 0.f;
    for (int pp = tid; pp < NPTS * NPTS; pp += 256) {
        int kk = pp / NPTS, ll = pp - kk * NPTS;
        float d = gl[kk] - gl[ll];
        acc3 += EXP2(-HL2E * d * d);
    }
    {
        double v = (double)acc3;
#pragma unroll
        for (int off = 32; off > 0; off >>= 1) v += __shfl_down(v, off, 64);
        if (lane == 0) t3red[wv] = v;
    }

    __syncthreads();
    if (tid == 0) {
        double t1 = 0.0;
#pragma unroll
        for (int n = 0; n < NM; ++n) t1 += cred[n];
        t1 /= (double)N_ELEM * (double)N_ELEM;
        double s2sum = (t2red[0] + t2red[1]) + (t2red[2] + t2red[3]);
        double t2 = -2.0 * s2sum / ((double)N_ELEM * (double)NPTS);
        double t3 = ((t3red[0] + t3red[1]) + (t3red[2] + t3red[3]))
                    / (double)(NPTS * NPTS);
        out[b] = (float)(t1 + t2 + t3);
    }
}

extern "C" void kernel_launch(void* const* d_in, const int* in_sizes, int n_in,
                              void* d_out, int out_size, void* d_ws, size_t ws_size,
                              hipStream_t stream) {
    const float* x = (const float*)d_in[0];
    float* out = (float*)d_out;
    hipLaunchKernelGGL(ep_fused, dim3(BATCH), dim3(256), 0, stream, x, out);
}

// Round 3
// 15.005 us; speedup vs baseline: 2.8318x; 1.6477x over previous
//
#include <hip/hip_runtime.h>
#include <math.h>

// Epps-Pulley statistic, B=16 rows of N=4096 fp32.
// Everything reduces to 48 weighted moments per row:
//   S_n = sum_i w_i xs_i^n,  w_i = exp(-xs_i^2/2)
//   term1 = (1/N^2) sum_n S_n^2 / n!          (Mercer expansion of the kernel)
//   term2 = (-2/NK) sum_k w_gk sum_n S_n g_k^n / n!
//   term3 = (1/K^2) sum_kl exp(-(g_k-g_l)^2/2)
// Kernel 1 (128 blocks = 16 rows x 8 slices): redundant row stats (f64) +
//   f32 moment chains + DPP wave reduction (VALU pipe, no LDS bpermute) ->
//   per-wave f32 partials to ws.  Kernel 2 (16 blocks): f64 combine.

#define N_ELEM 4096
#define BATCH  16
#define NPTS   17
#define NM     48                 // moments n = 0..47; tail < 1e-12
#define SPLIT  8                  // blocks per row
#define SLICE  (N_ELEM / SPLIT)   // 512 elems per block
#define NPART  (SPLIT * 4)        // wave-partials per row
#define L2E  1.4426950408889634f
#define HL2E 0.7213475204444817f  // 0.5*log2(e)

#if defined(__has_builtin)
#if __has_builtin(__builtin_amdgcn_exp2f)
#define EXP2(x) __builtin_amdgcn_exp2f(x)
#else
#define EXP2(x) exp2f(x)
#endif
#else
#define EXP2(x) exp2f(x)
#endif

// DPP-based wave64 reduction: 6 VALU adds, total lands in lane 63.
template<int CTRL, int RMASK>
__device__ __forceinline__ float dpp_add(float v) {
    int t = __builtin_amdgcn_update_dpp(0, __float_as_int(v), CTRL, RMASK, 0xf, false);
    return v + __int_as_float(t);
}
__device__ __forceinline__ float wave_sum63(float v) {
    v = dpp_add<0x111, 0xf>(v);   // row_shr:1
    v = dpp_add<0x112, 0xf>(v);   // row_shr:2
    v = dpp_add<0x114, 0xf>(v);   // row_shr:4
    v = dpp_add<0x118, 0xf>(v);   // row_shr:8  -> lane15 of each row = row sum
    v = dpp_add<0x142, 0xa>(v);   // row_bcast:15 into rows 1,3
    v = dpp_add<0x143, 0xc>(v);   // row_bcast:31 into rows 2,3 -> lane63 total
    return v;
}

// Giles' single-precision erfinv — matches XLA's f32 erfinv path.
__device__ __forceinline__ float erfinv_f(float y) {
    float w = -logf((1.0f - y) * (1.0f + y));
    float p;
    if (w < 5.0f) {
        w = w - 2.5f;
        p = 2.81022636e-08f;
        p = fmaf(p, w, 3.43273939e-07f);
        p = fmaf(p, w, -3.5233877e-06f);
        p = fmaf(p, w, -4.39150654e-06f);
        p = fmaf(p, w, 0.00021858087f);
        p = fmaf(p, w, -0.00125372503f);
        p = fmaf(p, w, -0.00417768164f);
        p = fmaf(p, w, 0.246640727f);
        p = fmaf(p, w, 1.50140941f);
    } else {
        w = sqrtf(w) - 3.0f;
        p = -0.000200214257f;
        p = fmaf(p, w, 0.000100950558f);
        p = fmaf(p, w, 0.00134934322f);
        p = fmaf(p, w, -0.00367342844f);
        p = fmaf(p, w, 0.00573950773f);
        p = fmaf(p, w, -0.0076224613f);
        p = fmaf(p, w, 0.00943887047f);
        p = fmaf(p, w, 1.00167406f);
        p = fmaf(p, w, 2.83297682f);
    }
    return p * y;
}

__global__ __launch_bounds__(256) void ep_moments(const float* __restrict__ x,
                                                  float* __restrict__ pm) {
    __shared__ double sred[8];
    __shared__ double stats[2];
    const int tid = threadIdx.x, lane = tid & 63, wv = tid >> 6;
    const int b = blockIdx.x / SPLIT, sl = blockIdx.x % SPLIT;
    const float* xr = x + b * N_ELEM;
    const float4* xr4 = (const float4*)xr;

    // ---- redundant full-row stats (f64) ----
    double s = 0.0, s2 = 0.0;
#pragma unroll
    for (int e = 0; e < 4; ++e) {
        float4 v = xr4[tid + 256 * e];
        double d0 = v.x, d1 = v.y, d2 = v.z, d3 = v.w;
        s  += (d0 + d1) + (d2 + d3);
        s2 += (d0 * d0 + d1 * d1) + (d2 * d2 + d3 * d3);
    }
#pragma unroll
    for (int off = 32; off > 0; off >>= 1) {
        s  += __shfl_down(s, off, 64);
        s2 += __shfl_down(s2, off, 64);
    }
    if (lane == 0) { sred[wv] = s; sred[4 + wv] = s2; }
    __syncthreads();
    if (tid == 0) {
        double Sa = (sred[0] + sred[1]) + (sred[2] + sred[3]);
        double Sb = (sred[4] + sred[5]) + (sred[6] + sred[7]);
        double mean = Sa / (double)N_ELEM;
        double var  = (Sb - (double)N_ELEM * mean * mean) / (double)(N_ELEM - 1);
        stats[0] = mean;
        stats[1] = 1.0 / (sqrt(var) + 1e-6);   // torch std(ddof=1) + EPS
    }
    __syncthreads();
    const double mean = stats[0], istd = stats[1];

    // ---- slice moments: 2 elems/thread, 48-term power chains ----
    float2 v2 = ((const float2*)(xr + sl * SLICE))[tid];
    float x0 = (float)(((double)v2.x - mean) * istd);
    float x1 = (float)(((double)v2.y - mean) * istd);
    float p0 = EXP2(-HL2E * x0 * x0);   // w = e^{-x^2/2}, chain start (n=0)
    float p1 = EXP2(-HL2E * x1 * x1);

    float S[NM];
#pragma unroll
    for (int n = 0; n < NM; ++n) { S[n] = p0 + p1; p0 *= x0; p1 *= x1; }

    // wave-reduce each moment on the VALU pipe; lane 63 holds wave totals
#pragma unroll
    for (int n = 0; n < NM; ++n) S[n] = wave_sum63(S[n]);

    if (lane == 63) {
        float4* dst = (float4*)(pm + (size_t)((b * SPLIT + sl) * 4 + wv) * NM);
#pragma unroll
        for (int q = 0; q < NM / 4; ++q)
            dst[q] = make_float4(S[4*q], S[4*q+1], S[4*q+2], S[4*q+3]);
    }
}

__global__ __launch_bounds__(64) void ep_finish(const float* __restrict__ pm,
                                                float* __restrict__ out) {
    __shared__ double SnL[NM], invfL[NM], cL[NM];
    __shared__ double t2L[NPTS], t3L[NPTS];
    __shared__ float gL[NPTS];
    const int b = blockIdx.x, tid = threadIdx.x;

    if (tid < NM) {
        const float* base = pm + (size_t)b * NPART * NM + tid;
        double acc = 0.0;
#pragma unroll
        for (int p = 0; p < NPART; ++p) acc += (double)base[(size_t)p * NM];
        double f = 1.0;
        for (int i = 2; i <= tid; ++i) f *= (double)i;   // n!
        SnL[tid] = acc;
        invfL[tid] = 1.0 / f;
        cL[tid] = acc * acc / f;
    }
    if (tid < NPTS) {
        float q = 0.01f + 0.06125f * (float)tid;   // linspace(0.01,0.99,17)
        gL[tid] = erfinv_f(2.0f * q - 1.0f) * 1.41421356237309515f;
    }
    __syncthreads();

    if (tid < NPTS) {
        double g = (double)gL[tid];
        // term2 row-sum via moments: w_g * sum_n S_n g^n / n!
        double pw = 1.0, acc = 0.0;
#pragma unroll
        for (int n = 0; n < NM; ++n) { acc += SnL[n] * invfL[n] * pw; pw *= g; }
        t2L[tid] = exp(-0.5 * g * g) * acc;
        // term3 partial row
        double a3 = 0.0;
        for (int l = 0; l < NPTS; ++l) {
            double d = g - (double)gL[l];
            a3 += exp(-0.5 * d * d);
        }
        t3L[tid] = a3;
    }
    __syncthreads();
    if (tid == 0) {
        double t1 = 0.0;
        for (int n = 0; n < NM; ++n) t1 += cL[n];
        t1 /= (double)N_ELEM * (double)N_ELEM;
        double s2 = 0.0, s3 = 0.0;
        for (int k = 0; k < NPTS; ++k) { s2 += t2L[k]; s3 += t3L[k]; }
        double t2 = -2.0 * s2 / ((double)N_ELEM * (double)NPTS);
        double t3 = s3 / (double)(NPTS * NPTS);
        out[b] = (float)(t1 + t2 + t3);
    }
}

extern "C" void kernel_launch(void* const* d_in, const int* in_sizes, int n_in,
                              void* d_out, int out_size, void* d_ws, size_t ws_size,
                              hipStream_t stream) {
    const float* x = (const float*)d_in[0];
    float* out = (float*)d_out;
    float* pm = (float*)d_ws;     // 16*32*48 f32 partial moments = 96 KB
    hipLaunchKernelGGL(ep_moments, dim3(BATCH * SPLIT), dim3(256), 0, stream, x, pm);
    hipLaunchKernelGGL(ep_finish, dim3(BATCH), dim3(64), 0, stream, pm, out);
}